// Round 2
// baseline (722.435 us; speedup 1.0000x reference)
//
#include <hip/hip_runtime.h>
#include <stdint.h>

// irreps linear: out[v,i] = (1/64) * sum_u x[u,i] * w[u,v], 4 paths,
// mul=4096, D in {1,3,5,7}. f32. Weights 256 MiB (= L3 size: L3-resident
// in steady-state replay).
//
// R5 -> R6 structural finding: dur_us contains ~321us of harness
// workspace-poison fills (2 x 1GiB @ ~160us, visible as fillBufferAligned
// in every profile; our kernel never cracks top-5 => our dispatches
// < 159us). Our true compute: R4 ~37us (single kernel), R5 ~44us
// (two-phase cost +7us). The "800 GB/s latency-bound" reading was the
// cold first iteration; steady-state weights stream from L3 at ~7 TB/s.
//
// R6: single kernel, no workspace. Attack instruction economics of the
// remaining ~37us: lane owns 8 consecutive v ->
//   - w loads become dwordx4 pairs: 4x fewer VMEM instrs, wave reads
//     2 KiB contiguous per u-visit (vs 67M scalar dwords in R4-struct).
//   - each LDS x-broadcast feeds 8 FMAs (vs 1): 8x fewer ds_reads/CU
//     (D=7 path was ~16-28K wave-LDS-instrs/CU -- the likely critical path).
// u-split across blocks (512 = 4 paths x 8 v-tiles x 16 u-chunks) finished
// with device-scope atomicAdd onto memset-zeroed out (1.05M adds total,
// ~3us) -- cheaper than R5's ws+p2 (+7us measured).
// Prediction: our portion 44 -> ~25-30us; dur_us 365 -> ~348.

constexpr int MUL = 4096;

// block geometry: v-span 512 (64 lanes x 8 v), u-span 256 (8 waves x 32 u)
// per-block w footprint: 512 KiB.

template<int D>
__device__ __forceinline__ void body(
    const float* __restrict__ w, const float* __restrict__ x,
    float* __restrict__ out, float* __restrict__ xs,
    int io_off, long w_off, int b128)
{
  const int t   = threadIdx.x;
  const int vg  = t & 63;          // lane -> 8-v group
  const int q   = t >> 6;          // wave -> 32-u subchunk
  const int vt  = b128 >> 4;       // 8 v-tiles of 512
  const int uc  = b128 & 15;       // 16 u-chunks of 256
  const int v0  = vt * 512 + vg * 8;
  const int u0g = uc * 256;

  // stage x slab (256 u x D floats, contiguous) into LDS
  for (int j = t; j < 256 * D; j += 512)
    xs[j] = x[io_off + u0g * D + j];
  __syncthreads();

  const float* __restrict__ wp = w + w_off + (long)u0g * MUL + v0;

  float acc[D][8];
  #pragma unroll
  for (int i = 0; i < D; ++i) {
    #pragma unroll
    for (int j = 0; j < 8; ++j) acc[i][j] = 0.f;
  }

  const int ub0 = q * 32;
  for (int ub = 0; ub < 32; ub += 4) {
    float4 wa[4], wb[4];
    #pragma unroll
    for (int k = 0; k < 4; ++k) {       // 8 x dwordx4 in flight per thread
      const float* p = wp + (long)(ub0 + ub + k) * MUL;
      wa[k] = *reinterpret_cast<const float4*>(p);
      wb[k] = *reinterpret_cast<const float4*>(p + 4);
    }
    #pragma unroll
    for (int k = 0; k < 4; ++k) {
      #pragma unroll
      for (int i = 0; i < D; ++i) {
        const float xv = xs[(ub0 + ub + k) * D + i];   // broadcast, 1 per 8 FMA
        acc[i][0] = fmaf(wa[k].x, xv, acc[i][0]);
        acc[i][1] = fmaf(wa[k].y, xv, acc[i][1]);
        acc[i][2] = fmaf(wa[k].z, xv, acc[i][2]);
        acc[i][3] = fmaf(wa[k].w, xv, acc[i][3]);
        acc[i][4] = fmaf(wb[k].x, xv, acc[i][4]);
        acc[i][5] = fmaf(wb[k].y, xv, acc[i][5]);
        acc[i][6] = fmaf(wb[k].z, xv, acc[i][6]);
        acc[i][7] = fmaf(wb[k].w, xv, acc[i][7]);
      }
    }
  }

  // finish: 16 u-chunks x 8 waves = 128 contributors per out element
  #pragma unroll
  for (int j = 0; j < 8; ++j) {
    #pragma unroll
    for (int i = 0; i < D; ++i)
      atomicAdd(out + io_off + (long)(v0 + j) * D + i, acc[i][j] * 0.015625f);
  }
}

__global__ __launch_bounds__(512)
void linear_fused(const float* __restrict__ w, const float* __restrict__ x,
                  float* __restrict__ out)
{
  __shared__ float xs[256 * 7];          // 7 KiB max (D=7)
  const int b    = blockIdx.x;           // 512 blocks = 4 paths x 128
  const int p    = b >> 7;
  const int b128 = b & 127;

  if      (p == 0) body<1>(w, x, out, xs,     0,         0L, b128);
  else if (p == 1) body<3>(w, x, out, xs,  4096,  16777216L, b128);
  else if (p == 2) body<5>(w, x, out, xs, 16384,  33554432L, b128);
  else             body<7>(w, x, out, xs, 36864,  50331648L, b128);
}

// ------------------------------------------------------------------------
extern "C" void kernel_launch(void* const* d_in, const int* in_sizes, int n_in,
                              void* d_out, int out_size, void* d_ws, size_t ws_size,
                              hipStream_t stream) {
  const float* x = (const float*)d_in[0];   // 65536 f32
  const float* w = (const float*)d_in[1];   // 67108864 f32
  hipMemsetAsync(d_out, 0, out_size, stream);           // out is poisoned
  linear_fused<<<512, 512, 0, stream>>>(w, x, (float*)d_out);
}

// Round 3
// 364.492 us; speedup vs baseline: 1.9820x; 1.9820x over previous
//
#include <hip/hip_runtime.h>
#include <stdint.h>

// irreps linear: out[v,i] = (1/64) * sum_u x[u,i] * w[u,v], 4 paths,
// mul=4096, D in {1,3,5,7}, f32. Weights 256 MiB read exactly once.
//
// Ledger (kernel-only portion; dur_us carries ~2x160us harness poison
// fills that partially overlap):
//   R4  single-kernel, scalar loads, no cross-block traffic : ~37us (dur 357.9)
//   R5  two-phase ws+p2                                     : ~44us (dur 365.3)
//   R6  atomicAdd finish: 467us/dispatch, WRITE_SIZE 256MiB (!)
//       -> 128-way same-address atomic contention + line-RMW write
//          amplification. Any cross-block reduction costs more than it saves.
//
// R7: keep R4's decomposition (256 blocks = 4 paths x 64 v-tiles; block
// reduces ALL u internally -> zero inter-block traffic, plain stores),
// fix R4's instruction economics:
//   - lane owns 4 consecutive v -> dwordx4 weight loads (16.8M VMEM
//     instrs vs R4's 67M scalar dwords; wave reads 4 rows x 256B).
//   - wave covers 4 u-rows per load instr (lane = colgrp(4) x row_sub(2));
//     each x LDS broadcast feeds 4 FMAs; compiler merges the D consecutive
//     x reads into b128/b64 (broadcast reads: bank-conflict-free).
//   - epilogue: 2 shfl_xor rounds (row_sub) + R4-style 16-way LDS reduce.
// Prediction: kernel 37 -> ~25-32us (memory-bound on L3/HBM mix),
// dur_us 722 -> ~345-358; WRITE_SIZE back to 0.25 MiB; fills re-enter top-5.

constexpr int MUL = 4096;

template<int D>
__device__ __forceinline__ void body(
    const float* __restrict__ w, const float* __restrict__ x,
    float* __restrict__ out, float* __restrict__ xs, float* __restrict__ red,
    int io_off, long w_off, int v0)
{
  const int t  = threadIdx.x;
  const int l  = t & 63;
  const int q  = t >> 6;          // wave 0..15 -> u stripe
  const int cg = l & 15;          // colgrp: v = v0 + cg*4 .. +3
  const int rs = l >> 4;          // row_sub 0..3

  const float* __restrict__ wp = w + w_off + v0 + (cg << 2);

  float acc[D][4];
  #pragma unroll
  for (int i = 0; i < D; ++i) {
    #pragma unroll
    for (int j = 0; j < 4; ++j) acc[i][j] = 0.f;
  }

  // 4 superchunks of 1024 u; wave q owns rows [q*64, q*64+64) of each.
  for (int sc = 0; sc < 4; ++sc) {
    __syncthreads();                       // protect xs from previous iter
    #pragma unroll
    for (int j = 0; j < D; ++j)            // stage 1024 x D floats, coalesced
      xs[t + j * 1024] = x[io_off + sc * 1024 * D + t + j * 1024];
    __syncthreads();

    const int rbase = q * 64;
    for (int bb = 0; bb < 16; bb += 8) {
      float4 wv[8];
      #pragma unroll
      for (int k = 0; k < 8; ++k) {        // 8 dwordx4 in flight per thread
        const int r = rbase + ((bb + k) << 2) + rs;
        wv[k] = *reinterpret_cast<const float4*>(
            wp + (long)(sc * 1024 + r) * MUL);
      }
      #pragma unroll
      for (int k = 0; k < 8; ++k) {
        const int r = rbase + ((bb + k) << 2) + rs;
        const float* xr = xs + r * D;      // consecutive -> b128/b64 merge
        #pragma unroll
        for (int i = 0; i < D; ++i) {
          acc[i][0] = fmaf(wv[k].x, xr[i], acc[i][0]);
          acc[i][1] = fmaf(wv[k].y, xr[i], acc[i][1]);
          acc[i][2] = fmaf(wv[k].z, xr[i], acc[i][2]);
          acc[i][3] = fmaf(wv[k].w, xr[i], acc[i][3]);
        }
      }
    }
  }

  // intra-wave reduce over row_sub (lane bits 4,5)
  #pragma unroll
  for (int i = 0; i < D; ++i) {
    #pragma unroll
    for (int j = 0; j < 4; ++j) {
      acc[i][j] += __shfl_xor(acc[i][j], 16);
      acc[i][j] += __shfl_xor(acc[i][j], 32);
    }
  }

  __syncthreads();                          // xs reads done; red is separate
  if (rs == 0) {
    #pragma unroll
    for (int j = 0; j < 4; ++j) {
      #pragma unroll
      for (int i = 0; i < D; ++i)
        red[(q * 64 + (cg << 2) + j) * D + i] = acc[i][j];
    }
  }
  __syncthreads();

  // final 16-way sum over waves; 64*D contiguous floats per block
  for (int o = t; o < 64 * D; o += 1024) {
    float s = 0.f;
    #pragma unroll
    for (int qq = 0; qq < 16; ++qq) s += red[qq * 64 * D + o];
    out[io_off + v0 * D + o] = s * 0.015625f;
  }
}

__global__ __launch_bounds__(1024, 4)
void linear_all(const float* __restrict__ w, const float* __restrict__ x,
                float* __restrict__ out)
{
  __shared__ float xs [1024 * 7];        // 28 KiB
  __shared__ float red[16 * 64 * 7];     // 28 KiB
  const int b  = blockIdx.x;             // 256 = 4 paths x 64 v-tiles
  const int p  = b >> 6;
  const int v0 = (b & 63) * 64;

  if      (p == 0) body<1>(w, x, out, xs, red,     0,         0L, v0);
  else if (p == 1) body<3>(w, x, out, xs, red,  4096,  16777216L, v0);
  else if (p == 2) body<5>(w, x, out, xs, red, 16384,  33554432L, v0);
  else             body<7>(w, x, out, xs, red, 36864,  50331648L, v0);
}

// ------------------------------------------------------------------------
extern "C" void kernel_launch(void* const* d_in, const int* in_sizes, int n_in,
                              void* d_out, int out_size, void* d_ws, size_t ws_size,
                              hipStream_t stream) {
  const float* x = (const float*)d_in[0];   // 65536 f32
  const float* w = (const float*)d_in[1];   // 67108864 f32
  linear_all<<<256, 1024, 0, stream>>>(w, x, (float*)d_out);
}